// Round 1
// baseline (3167.368 us; speedup 1.0000x reference)
//
#include <hip/hip_runtime.h>
#include <cstdint>
#include <cstddef>

#define CCH 128   // channels
#define G4  512   // 4*H gate dim

__device__ __forceinline__ float sigmoidf_(float x) {
    return 1.0f / (1.0f + __expf(-x));
}

// out[k*R + j] = in[j*Cc + k]   (in: [R][Cc] row-major -> out: [Cc][R])
__global__ __launch_bounds__(256) void transpose_kernel(
    const float* __restrict__ in, float* __restrict__ out, int R, int Cc)
{
    int t = blockIdx.x * 256 + threadIdx.x;
    if (t >= R * Cc) return;
    int j = t / Cc;
    int k = t - j * Cc;
    out[k * R + j] = in[t];
}

// msg = o * tanh(sigmoid(i) * tanh(g)), gates = x @ W_ih^T + b  (f-gate skipped)
// WT: [128][512] = W_ih transposed.  32 nodes/block, 256 threads.
// thread: c = tid&63 -> columns {c, c+64}; r = tid>>6 -> nodes r*8..r*8+7.
__global__ __launch_bounds__(256) void lstm_msg_kernel(
    const float* __restrict__ x,    // [N,128]
    const float* __restrict__ WT,   // [128,512]
    const float* __restrict__ b,    // [512]
    float* __restrict__ msg,        // [N,128]
    int N)
{
    __shared__ float xs[32][CCH];
    const int tid = threadIdx.x;
    const int nb = blockIdx.x * 32;
    {
        const float4* srcp = (const float4*)(x + (size_t)nb * CCH);
        float4* dstp = (float4*)(&xs[0][0]);
        const int nvalid = (min(32, N - nb)) * (CCH / 4);
        for (int i = tid; i < 32 * (CCH / 4); i += 256)
            if (i < nvalid) dstp[i] = srcp[i];
    }
    __syncthreads();
    const int c = tid & 63;
    const int r = tid >> 6;

    float accI[2][8], accG[2][8], accO[2][8];
#pragma unroll
    for (int u = 0; u < 2; u++)
#pragma unroll
        for (int m = 0; m < 8; m++) { accI[u][m] = 0.f; accG[u][m] = 0.f; accO[u][m] = 0.f; }

    for (int k = 0; k < CCH; k += 4) {
        float wI[2][4], wG[2][4], wO[2][4];
#pragma unroll
        for (int kk = 0; kk < 4; kk++) {
            const float* wrow = WT + (size_t)(k + kk) * G4;
            wI[0][kk] = wrow[c];           wI[1][kk] = wrow[c + 64];
            wG[0][kk] = wrow[256 + c];     wG[1][kk] = wrow[256 + c + 64];
            wO[0][kk] = wrow[384 + c];     wO[1][kk] = wrow[384 + c + 64];
        }
#pragma unroll
        for (int m = 0; m < 8; m++) {
            float4 xv = *(const float4*)(&xs[r * 8 + m][k]);
#pragma unroll
            for (int u = 0; u < 2; u++) {
                accI[u][m] += xv.x * wI[u][0] + xv.y * wI[u][1] + xv.z * wI[u][2] + xv.w * wI[u][3];
                accG[u][m] += xv.x * wG[u][0] + xv.y * wG[u][1] + xv.z * wG[u][2] + xv.w * wG[u][3];
                accO[u][m] += xv.x * wO[u][0] + xv.y * wO[u][1] + xv.z * wO[u][2] + xv.w * wO[u][3];
            }
        }
    }

#pragma unroll
    for (int u = 0; u < 2; u++) {
        const int cc = c + u * 64;
        const float bi = b[cc], bg = b[256 + cc], bo = b[384 + cc];
#pragma unroll
        for (int m = 0; m < 8; m++) {
            const int n = nb + r * 8 + m;
            if (n < N) {
                float iv = sigmoidf_(accI[u][m] + bi);
                float gv = tanhf(accG[u][m] + bg);
                float ov = sigmoidf_(accO[u][m] + bo);
                float cs = iv * gv;
                msg[(size_t)n * CCH + cc] = ov * tanhf(cs);
            }
        }
    }
}

// aggr[dst] += msg[src]; 32 lanes per edge, float4 per lane.
__global__ __launch_bounds__(256) void scatter_kernel(
    const int* __restrict__ src, const int* __restrict__ dst,
    const float* __restrict__ msg, float* __restrict__ aggr, int E)
{
    const int lane = threadIdx.x & 31;
    const int eloc = threadIdx.x >> 5;
    const long long e = (long long)blockIdx.x * 8 + eloc;
    if (e >= E) return;
    const int s = src[e];
    const int d = dst[e];
    const float4 v = *(const float4*)(msg + (size_t)s * CCH + lane * 4);
    float* base = aggr + (size_t)d * CCH + lane * 4;
    atomicAdd(base + 0, v.x);
    atomicAdd(base + 1, v.y);
    atomicAdd(base + 2, v.z);
    atomicAdd(base + 3, v.w);
}

// out = relu([x_dst | aggr] @ W_lin^T + b_lin);  WT2: [256][128] transposed W_lin.
__global__ __launch_bounds__(256) void linear_relu_kernel(
    const float* __restrict__ xd,   // [N,128]
    const float* __restrict__ ag,   // [N,128]
    const float* __restrict__ WT2,  // [256,128]
    const float* __restrict__ bl,   // [128]
    float* __restrict__ out,        // [N,128]
    int N)
{
    __shared__ float xs[32][CCH];
    __shared__ float as_[32][CCH];
    const int tid = threadIdx.x;
    const int nb = blockIdx.x * 32;
    {
        const float4* s1 = (const float4*)(xd + (size_t)nb * CCH);
        const float4* s2 = (const float4*)(ag + (size_t)nb * CCH);
        float4* d1 = (float4*)(&xs[0][0]);
        float4* d2 = (float4*)(&as_[0][0]);
        const int nvalid = (min(32, N - nb)) * (CCH / 4);
        for (int i = tid; i < 32 * (CCH / 4); i += 256) {
            if (i < nvalid) { d1[i] = s1[i]; d2[i] = s2[i]; }
        }
    }
    __syncthreads();
    const int c = tid & 63;
    const int r = tid >> 6;

    float acc[2][8];
#pragma unroll
    for (int u = 0; u < 2; u++)
#pragma unroll
        for (int m = 0; m < 8; m++) acc[u][m] = 0.f;

    for (int k = 0; k < CCH; k += 4) {
        float wx[2][4], wa[2][4];
#pragma unroll
        for (int kk = 0; kk < 4; kk++) {
            const float* row1 = WT2 + (size_t)(k + kk) * CCH;
            const float* row2 = WT2 + (size_t)(CCH + k + kk) * CCH;
            wx[0][kk] = row1[c]; wx[1][kk] = row1[c + 64];
            wa[0][kk] = row2[c]; wa[1][kk] = row2[c + 64];
        }
#pragma unroll
        for (int m = 0; m < 8; m++) {
            float4 xv = *(const float4*)(&xs[r * 8 + m][k]);
            float4 av = *(const float4*)(&as_[r * 8 + m][k]);
#pragma unroll
            for (int u = 0; u < 2; u++) {
                acc[u][m] += xv.x * wx[u][0] + xv.y * wx[u][1] + xv.z * wx[u][2] + xv.w * wx[u][3]
                           + av.x * wa[u][0] + av.y * wa[u][1] + av.z * wa[u][2] + av.w * wa[u][3];
            }
        }
    }

#pragma unroll
    for (int u = 0; u < 2; u++) {
        const int cc = c + u * 64;
        const float bv = bl[cc];
#pragma unroll
        for (int m = 0; m < 8; m++) {
            const int n = nb + r * 8 + m;
            if (n < N) out[(size_t)n * CCH + cc] = fmaxf(acc[u][m] + bv, 0.0f);
        }
    }
}

extern "C" void kernel_launch(void* const* d_in, const int* in_sizes, int n_in,
                              void* d_out, int out_size, void* d_ws, size_t ws_size,
                              hipStream_t stream) {
    const float* x_a      = (const float*)d_in[0];
    const float* x_b      = (const float*)d_in[1];
    const int*   e_ab     = (const int*)d_in[2];
    const int*   e_ba     = (const int*)d_in[3];
    const float* W_ih_ab  = (const float*)d_in[4];
    const float* b_ab     = (const float*)d_in[5];
    const float* W_lin_ab = (const float*)d_in[6];
    const float* b_lin_ab = (const float*)d_in[7];
    const float* W_ih_ba  = (const float*)d_in[8];
    const float* b_ba     = (const float*)d_in[9];
    const float* W_lin_ba = (const float*)d_in[10];
    const float* b_lin_ba = (const float*)d_in[11];

    const int NA = in_sizes[0] / CCH;
    const int NB = in_sizes[1] / CCH;
    const int E  = in_sizes[2] / 2;

    float* out = (float*)d_out;
    char* ws = (char*)d_ws;

    // workspace layout
    float* WT_ih_ab  = (float*)(ws);                       // 128*512 f = 256 KB
    float* WT_ih_ba  = (float*)(ws + 262144);              // 256 KB
    float* WT_lin_ab = (float*)(ws + 524288);              // 256*128 f = 128 KB
    float* WT_lin_ba = (float*)(ws + 655360);              // 128 KB
    float* msg_a     = (float*)(ws + 786432);              // NA*128 f
    float* msg_b     = msg_a + (size_t)NA * CCH;           // NB*128 f
    float* aggr_b    = msg_b + (size_t)NB * CCH;           // NB*128 f
    float* aggr_a    = aggr_b + (size_t)NB * CCH;          // NA*128 f

    // zero both aggregation buffers (contiguous)
    hipMemsetAsync(aggr_b, 0, (size_t)(NA + NB) * CCH * sizeof(float), stream);

    // weight transposes
    transpose_kernel<<<(512 * 128 + 255) / 256, 256, 0, stream>>>(W_ih_ab, WT_ih_ab, 512, 128);
    transpose_kernel<<<(512 * 128 + 255) / 256, 256, 0, stream>>>(W_ih_ba, WT_ih_ba, 512, 128);
    transpose_kernel<<<(128 * 256 + 255) / 256, 256, 0, stream>>>(W_lin_ab, WT_lin_ab, 128, 256);
    transpose_kernel<<<(128 * 256 + 255) / 256, 256, 0, stream>>>(W_lin_ba, WT_lin_ba, 128, 256);

    // relation a->b (updates type-b nodes)
    lstm_msg_kernel<<<(NA + 31) / 32, 256, 0, stream>>>(x_a, WT_ih_ab, b_ab, msg_a, NA);
    // relation b->a (updates type-a nodes)
    lstm_msg_kernel<<<(NB + 31) / 32, 256, 0, stream>>>(x_b, WT_ih_ba, b_ba, msg_b, NB);

    scatter_kernel<<<(E + 7) / 8, 256, 0, stream>>>(e_ab, e_ab + E, msg_a, aggr_b, E);
    scatter_kernel<<<(E + 7) / 8, 256, 0, stream>>>(e_ba, e_ba + E, msg_b, aggr_a, E);

    // out layout: [2, N, 128]: index 0 = out_a, index 1 = out_b
    linear_relu_kernel<<<(NB + 31) / 32, 256, 0, stream>>>(x_b, aggr_b, WT_lin_ab, b_lin_ab,
                                                           out + (size_t)NA * CCH, NB);
    linear_relu_kernel<<<(NA + 31) / 32, 256, 0, stream>>>(x_a, aggr_a, WT_lin_ba, b_lin_ba,
                                                           out, NA);
}

// Round 2
// 745.756 us; speedup vs baseline: 4.2472x; 4.2472x over previous
//
#include <hip/hip_runtime.h>
#include <cstdint>
#include <cstddef>

#define CCH 128   // channels
#define G4  512   // 4*H gate dim

__device__ __forceinline__ float sigmoidf_(float x) {
    return 1.0f / (1.0f + __expf(-x));
}

// out[k*R + j] = in[j*Cc + k]
__global__ __launch_bounds__(256) void transpose_kernel(
    const float* __restrict__ in, float* __restrict__ out, int R, int Cc)
{
    int t = blockIdx.x * 256 + threadIdx.x;
    if (t >= R * Cc) return;
    int j = t / Cc;
    int k = t - j * Cc;
    out[k * R + j] = in[t];
}

// msg = o * tanh(sigmoid(i) * tanh(g)), gates = x @ W_ih^T + b  (f-gate dead, c0=0)
__global__ __launch_bounds__(256) void lstm_msg_kernel(
    const float* __restrict__ x,    // [N,128]
    const float* __restrict__ WT,   // [128,512]
    const float* __restrict__ b,    // [512]
    float* __restrict__ msg,        // [N,128]
    int N)
{
    __shared__ float xs[32][CCH];
    const int tid = threadIdx.x;
    const int nb = blockIdx.x * 32;
    {
        const float4* srcp = (const float4*)(x + (size_t)nb * CCH);
        float4* dstp = (float4*)(&xs[0][0]);
        const int nvalid = (min(32, N - nb)) * (CCH / 4);
        for (int i = tid; i < 32 * (CCH / 4); i += 256)
            if (i < nvalid) dstp[i] = srcp[i];
    }
    __syncthreads();
    const int c = tid & 63;
    const int r = tid >> 6;

    float accI[2][8], accG[2][8], accO[2][8];
#pragma unroll
    for (int u = 0; u < 2; u++)
#pragma unroll
        for (int m = 0; m < 8; m++) { accI[u][m] = 0.f; accG[u][m] = 0.f; accO[u][m] = 0.f; }

    for (int k = 0; k < CCH; k += 4) {
        float wI[2][4], wG[2][4], wO[2][4];
#pragma unroll
        for (int kk = 0; kk < 4; kk++) {
            const float* wrow = WT + (size_t)(k + kk) * G4;
            wI[0][kk] = wrow[c];           wI[1][kk] = wrow[c + 64];
            wG[0][kk] = wrow[256 + c];     wG[1][kk] = wrow[256 + c + 64];
            wO[0][kk] = wrow[384 + c];     wO[1][kk] = wrow[384 + c + 64];
        }
#pragma unroll
        for (int m = 0; m < 8; m++) {
            float4 xv = *(const float4*)(&xs[r * 8 + m][k]);
#pragma unroll
            for (int u = 0; u < 2; u++) {
                accI[u][m] += xv.x * wI[u][0] + xv.y * wI[u][1] + xv.z * wI[u][2] + xv.w * wI[u][3];
                accG[u][m] += xv.x * wG[u][0] + xv.y * wG[u][1] + xv.z * wG[u][2] + xv.w * wG[u][3];
                accO[u][m] += xv.x * wO[u][0] + xv.y * wO[u][1] + xv.z * wO[u][2] + xv.w * wO[u][3];
            }
        }
    }

#pragma unroll
    for (int u = 0; u < 2; u++) {
        const int cc = c + u * 64;
        const float bi = b[cc], bg = b[256 + cc], bo = b[384 + cc];
#pragma unroll
        for (int m = 0; m < 8; m++) {
            const int n = nb + r * 8 + m;
            if (n < N) {
                float iv = sigmoidf_(accI[u][m] + bi);
                float gv = tanhf(accG[u][m] + bg);
                float ov = sigmoidf_(accO[u][m] + bo);
                msg[(size_t)n * CCH + cc] = ov * tanhf(iv * gv);
            }
        }
    }
}

// ---- CSR build ----
__global__ __launch_bounds__(256) void hist_kernel(
    const int* __restrict__ dst, int* __restrict__ deg, int E)
{
    int e = blockIdx.x * 256 + threadIdx.x;
    if (e < E) atomicAdd(&deg[dst[e]], 1);
}

// per-256-block inclusive scan; block totals to bsum
__global__ __launch_bounds__(256) void scan1_kernel(
    const int* __restrict__ deg, int* __restrict__ incl, int* __restrict__ bsum, int N)
{
    __shared__ int s[256];
    const int tid = threadIdx.x;
    const int i = blockIdx.x * 256 + tid;
    int v = (i < N) ? deg[i] : 0;
    s[tid] = v; __syncthreads();
#pragma unroll
    for (int off = 1; off < 256; off <<= 1) {
        int t = (tid >= off) ? s[tid - off] : 0;
        __syncthreads();
        s[tid] += t;
        __syncthreads();
    }
    if (i < N) incl[i] = s[tid];
    if (tid == 255) bsum[blockIdx.x] = s[255];
}

// single-block exclusive scan of block sums (nb <= 256)
__global__ __launch_bounds__(256) void scan2_kernel(int* __restrict__ bsum, int nb)
{
    __shared__ int s[256];
    const int tid = threadIdx.x;
    int v = (tid < nb) ? bsum[tid] : 0;
    s[tid] = v; __syncthreads();
#pragma unroll
    for (int off = 1; off < 256; off <<= 1) {
        int t = (tid >= off) ? s[tid - off] : 0;
        __syncthreads();
        s[tid] += t;
        __syncthreads();
    }
    if (tid < nb) bsum[tid] = s[tid] - v;   // exclusive
}

// offs[i] = exclusive prefix; also init cursor
__global__ __launch_bounds__(256) void scan3_kernel(
    const int* __restrict__ incl, const int* __restrict__ deg, const int* __restrict__ bsum,
    int* __restrict__ offs, int* __restrict__ cursor, int N)
{
    int i = blockIdx.x * 256 + threadIdx.x;
    if (i < N) {
        int o = incl[i] - deg[i] + bsum[i >> 8];
        offs[i] = o;
        cursor[i] = o;
    }
}

__global__ __launch_bounds__(256) void fill_kernel(
    const int* __restrict__ src, const int* __restrict__ dst,
    int* __restrict__ cursor, int* __restrict__ csr_src, int E)
{
    int e = blockIdx.x * 256 + threadIdx.x;
    if (e < E) {
        int p = atomicAdd(&cursor[dst[e]], 1);
        csr_src[p] = src[e];
    }
}

// out = relu([x_dst | segment_sum(msg[src])] @ W_lin^T + b_lin)
// 32 dst nodes per block. Gather: wave w handles nodes w*8..w*8+7, 2 ch/lane.
__global__ __launch_bounds__(256) void gather_linear_relu_kernel(
    const float* __restrict__ xd,       // [N,128]
    const float* __restrict__ msg,      // [Nsrc,128]
    const int* __restrict__ csr_src,
    const int* __restrict__ offs,
    const int* __restrict__ deg,
    const float* __restrict__ WT2,      // [256,128]
    const float* __restrict__ bl,       // [128]
    float* __restrict__ out,            // [N,128]
    int N)
{
    __shared__ float xs[32][CCH];
    __shared__ float as_[32][CCH];
    const int tid = threadIdx.x;
    const int nb = blockIdx.x * 32;

    {   // stage x_dst
        const float4* s1 = (const float4*)(xd + (size_t)nb * CCH);
        float4* d1 = (float4*)(&xs[0][0]);
        const int nvalid = (min(32, N - nb)) * (CCH / 4);
        for (int i = tid; i < 32 * (CCH / 4); i += 256)
            if (i < nvalid) d1[i] = s1[i];
    }
    {   // gather segment sums into as_
        const int lane = tid & 63;
        const int wv = tid >> 6;
        const float* colbase = msg + lane * 2;
#pragma unroll
        for (int m = 0; m < 8; m++) {
            const int nloc = wv * 8 + m;
            const int n = nb + nloc;
            float ax = 0.f, ay = 0.f;
            if (n < N) {
                const int start = offs[n];
                const int cnt = deg[n];
                int j = 0;
                for (; j + 4 <= cnt; j += 4) {
                    const int s0 = csr_src[start + j];
                    const int s1 = csr_src[start + j + 1];
                    const int s2 = csr_src[start + j + 2];
                    const int s3 = csr_src[start + j + 3];
                    float2 v0 = *(const float2*)(colbase + (size_t)s0 * CCH);
                    float2 v1 = *(const float2*)(colbase + (size_t)s1 * CCH);
                    float2 v2 = *(const float2*)(colbase + (size_t)s2 * CCH);
                    float2 v3 = *(const float2*)(colbase + (size_t)s3 * CCH);
                    ax += v0.x + v1.x + v2.x + v3.x;
                    ay += v0.y + v1.y + v2.y + v3.y;
                }
                for (; j < cnt; j++) {
                    const int s0 = csr_src[start + j];
                    float2 v0 = *(const float2*)(colbase + (size_t)s0 * CCH);
                    ax += v0.x; ay += v0.y;
                }
            }
            float2* dst2 = (float2*)(&as_[nloc][lane * 2]);
            dst2->x = ax; dst2->y = ay;
        }
    }
    __syncthreads();

    const int c = tid & 63;
    const int r = tid >> 6;
    float acc[2][8];
#pragma unroll
    for (int u = 0; u < 2; u++)
#pragma unroll
        for (int m = 0; m < 8; m++) acc[u][m] = 0.f;

    for (int k = 0; k < CCH; k += 4) {
        float wx[2][4], wa[2][4];
#pragma unroll
        for (int kk = 0; kk < 4; kk++) {
            const float* row1 = WT2 + (size_t)(k + kk) * CCH;
            const float* row2 = WT2 + (size_t)(CCH + k + kk) * CCH;
            wx[0][kk] = row1[c]; wx[1][kk] = row1[c + 64];
            wa[0][kk] = row2[c]; wa[1][kk] = row2[c + 64];
        }
#pragma unroll
        for (int m = 0; m < 8; m++) {
            float4 xv = *(const float4*)(&xs[r * 8 + m][k]);
            float4 av = *(const float4*)(&as_[r * 8 + m][k]);
#pragma unroll
            for (int u = 0; u < 2; u++) {
                acc[u][m] += xv.x * wx[u][0] + xv.y * wx[u][1] + xv.z * wx[u][2] + xv.w * wx[u][3]
                           + av.x * wa[u][0] + av.y * wa[u][1] + av.z * wa[u][2] + av.w * wa[u][3];
            }
        }
    }

#pragma unroll
    for (int u = 0; u < 2; u++) {
        const int cc = c + u * 64;
        const float bv = bl[cc];
#pragma unroll
        for (int m = 0; m < 8; m++) {
            const int n = nb + r * 8 + m;
            if (n < N) out[(size_t)n * CCH + cc] = fmaxf(acc[u][m] + bv, 0.0f);
        }
    }
}

extern "C" void kernel_launch(void* const* d_in, const int* in_sizes, int n_in,
                              void* d_out, int out_size, void* d_ws, size_t ws_size,
                              hipStream_t stream) {
    const float* x_a      = (const float*)d_in[0];
    const float* x_b      = (const float*)d_in[1];
    const int*   e_ab     = (const int*)d_in[2];
    const int*   e_ba     = (const int*)d_in[3];
    const float* W_ih_ab  = (const float*)d_in[4];
    const float* b_ab     = (const float*)d_in[5];
    const float* W_lin_ab = (const float*)d_in[6];
    const float* b_lin_ab = (const float*)d_in[7];
    const float* W_ih_ba  = (const float*)d_in[8];
    const float* b_ba     = (const float*)d_in[9];
    const float* W_lin_ba = (const float*)d_in[10];
    const float* b_lin_ba = (const float*)d_in[11];

    const int NA = in_sizes[0] / CCH;
    const int NB = in_sizes[1] / CCH;
    const int E  = in_sizes[2] / 2;

    float* out = (float*)d_out;
    char* ws = (char*)d_ws;
    size_t off = 0;
    auto alloc = [&](size_t bytes) { char* p = ws + off; off += (bytes + 255) & ~(size_t)255; return p; };

    float* WT_ih_ab  = (float*)alloc(512 * 128 * 4);
    float* WT_ih_ba  = (float*)alloc(512 * 128 * 4);
    float* WT_lin_ab = (float*)alloc(256 * 128 * 4);
    float* WT_lin_ba = (float*)alloc(256 * 128 * 4);
    float* msg_a     = (float*)alloc((size_t)NA * CCH * 4);
    float* msg_b     = (float*)alloc((size_t)NB * CCH * 4);
    int*   deg_b     = (int*)alloc((size_t)NB * 4);   // deg region (contiguous for one memset)
    int*   deg_a     = (int*)alloc((size_t)NA * 4);
    int*   incl_b    = (int*)alloc((size_t)NB * 4);
    int*   incl_a    = (int*)alloc((size_t)NA * 4);
    int*   bsum_b    = (int*)alloc(256 * 4);
    int*   bsum_a    = (int*)alloc(256 * 4);
    int*   offs_b    = (int*)alloc((size_t)NB * 4);
    int*   offs_a    = (int*)alloc((size_t)NA * 4);
    int*   cur_b     = (int*)alloc((size_t)NB * 4);
    int*   cur_a     = (int*)alloc((size_t)NA * 4);
    int*   csr_ab    = (int*)alloc((size_t)E * 4);
    int*   csr_ba    = (int*)alloc((size_t)E * 4);

    const int nbB = (NB + 255) / 256;   // scan blocks (<=256 assumed; N=50000 -> 196)
    const int nbA = (NA + 255) / 256;

    // zero degree histograms (deg_b and deg_a are adjacent modulo 256B pad; memset both)
    hipMemsetAsync(deg_b, 0, ((size_t)NB * 4 + 255 & ~(size_t)255) + (size_t)NA * 4, stream);

    transpose_kernel<<<(512 * 128 + 255) / 256, 256, 0, stream>>>(W_ih_ab, WT_ih_ab, 512, 128);
    transpose_kernel<<<(512 * 128 + 255) / 256, 256, 0, stream>>>(W_ih_ba, WT_ih_ba, 512, 128);
    transpose_kernel<<<(128 * 256 + 255) / 256, 256, 0, stream>>>(W_lin_ab, WT_lin_ab, 128, 256);
    transpose_kernel<<<(128 * 256 + 255) / 256, 256, 0, stream>>>(W_lin_ba, WT_lin_ba, 128, 256);

    // LSTM messages per source node
    lstm_msg_kernel<<<(NA + 31) / 32, 256, 0, stream>>>(x_a, WT_ih_ab, b_ab, msg_a, NA);
    lstm_msg_kernel<<<(NB + 31) / 32, 256, 0, stream>>>(x_b, WT_ih_ba, b_ba, msg_b, NB);

    // CSR build: relation a->b buckets by dst in B; b->a buckets by dst in A
    hist_kernel<<<(E + 255) / 256, 256, 0, stream>>>(e_ab + E, deg_b, E);
    hist_kernel<<<(E + 255) / 256, 256, 0, stream>>>(e_ba + E, deg_a, E);

    scan1_kernel<<<nbB, 256, 0, stream>>>(deg_b, incl_b, bsum_b, NB);
    scan1_kernel<<<nbA, 256, 0, stream>>>(deg_a, incl_a, bsum_a, NA);
    scan2_kernel<<<1, 256, 0, stream>>>(bsum_b, nbB);
    scan2_kernel<<<1, 256, 0, stream>>>(bsum_a, nbA);
    scan3_kernel<<<nbB, 256, 0, stream>>>(incl_b, deg_b, bsum_b, offs_b, cur_b, NB);
    scan3_kernel<<<nbA, 256, 0, stream>>>(incl_a, deg_a, bsum_a, offs_a, cur_a, NA);

    fill_kernel<<<(E + 255) / 256, 256, 0, stream>>>(e_ab, e_ab + E, cur_b, csr_ab, E);
    fill_kernel<<<(E + 255) / 256, 256, 0, stream>>>(e_ba, e_ba + E, cur_a, csr_ba, E);

    // fused gather + linear + relu;  out layout [2,N,128]: 0 = out_a, 1 = out_b
    gather_linear_relu_kernel<<<(NB + 31) / 32, 256, 0, stream>>>(
        x_b, msg_a, csr_ab, offs_b, deg_b, WT_lin_ab, b_lin_ab, out + (size_t)NA * CCH, NB);
    gather_linear_relu_kernel<<<(NA + 31) / 32, 256, 0, stream>>>(
        x_a, msg_b, csr_ba, offs_a, deg_a, WT_lin_ba, b_lin_ba, out, NA);
}

// Round 3
// 451.310 us; speedup vs baseline: 7.0182x; 1.6524x over previous
//
#include <hip/hip_runtime.h>
#include <cstdint>
#include <cstddef>

#define CCH 128

typedef __attribute__((ext_vector_type(8))) short short8;
typedef __attribute__((ext_vector_type(4))) float floatx4;

__device__ __forceinline__ unsigned short f2bf(float f) {
    unsigned u = __builtin_bit_cast(unsigned, f);
    u += 0x7fffu + ((u >> 16) & 1u);   // RNE
    return (unsigned short)(u >> 16);
}
__device__ __forceinline__ float bf2f(unsigned short h) {
    unsigned u = ((unsigned)h) << 16;
    return __builtin_bit_cast(float, u);
}
__device__ __forceinline__ float sigmoidf_(float x) { return 1.0f / (1.0f + __expf(-x)); }

// ---------------- weight prep: fragment-ready bf16 ----------------
// W_ih frag layout: [rel][g(3)][ct(8)][kc(4)][lane(64)][j(8)]; gates {i,g,o} -> rows {0,256,384}
__global__ __launch_bounds__(256) void prep_wih_kernel(
    const float* __restrict__ W0, const float* __restrict__ W1,
    unsigned short* __restrict__ frag)
{
    int t = blockIdx.x * 256 + threadIdx.x;           // 2*3*8*4*64 = 12288
    if (t >= 12288) return;
    int l  = t & 63;
    int kc = (t >> 6) & 3;
    int ct = (t >> 8) & 7;
    int g  = (t >> 11) % 3;
    int rel = t / 6144;
    int gb = (g == 0) ? 0 : (g == 1 ? 256 : 384);
    const float* W = rel ? W1 : W0;
    int n  = gb + ct * 16 + (l & 15);
    int kb = kc * 32 + (l >> 4) * 8;
    unsigned short* o = frag + (size_t)t * 8;
#pragma unroll
    for (int j = 0; j < 8; j++) o[j] = f2bf(W[(size_t)n * CCH + kb + j]);
}

// W_lin frag layout: [rel][ct(8)][kc(8)][lane(64)][j(8)]; W_lin is [128][256]
__global__ __launch_bounds__(256) void prep_wlin_kernel(
    const float* __restrict__ W0, const float* __restrict__ W1,
    unsigned short* __restrict__ frag)
{
    int t = blockIdx.x * 256 + threadIdx.x;           // 2*8*8*64 = 8192
    if (t >= 8192) return;
    int l  = t & 63;
    int kc = (t >> 6) & 7;
    int ct = (t >> 9) & 7;
    int rel = t >> 12;
    const float* W = rel ? W1 : W0;
    int n  = ct * 16 + (l & 15);
    int kb = kc * 32 + (l >> 4) * 8;
    unsigned short* o = frag + (size_t)t * 8;
#pragma unroll
    for (int j = 0; j < 8; j++) o[j] = f2bf(W[(size_t)n * 256 + kb + j]);
}

// ---------------- LSTM message via MFMA ----------------
#define XPAD 136   // 128 + 8 bf16 pad (row stride 272 B -> bank shift 4/row, 2-way = free)
__global__ __launch_bounds__(256) void lstm_mfma_kernel(
    const float* __restrict__ x0, const float* __restrict__ x1,
    const unsigned short* __restrict__ wfrag,
    const float* __restrict__ b0, const float* __restrict__ b1,
    unsigned short* __restrict__ msg0, unsigned short* __restrict__ msg1,
    int N0, int N1, int nblk0)
{
    __shared__ unsigned short xs[32 * XPAD];
    const int rel = (blockIdx.x >= nblk0);
    const int nb = (rel ? (blockIdx.x - nblk0) : blockIdx.x) * 32;
    const float* x = rel ? x1 : x0;
    const float* bias = rel ? b1 : b0;
    unsigned short* msg = rel ? msg1 : msg0;
    const int N = rel ? N1 : N0;
    const unsigned short* wf = wfrag + (size_t)rel * 6144 * 8;

    {   // stage 32 rows of x as bf16
        int t = threadIdx.x;
        int r = t >> 3;                 // 8 threads/row
        int c0 = (t & 7) * 16;
        int n = nb + r;
        unsigned short* dstp = xs + r * XPAD + c0;
        if (n < N) {
            const float4* srcp = (const float4*)(x + (size_t)n * CCH + c0);
#pragma unroll
            for (int qq = 0; qq < 4; qq++) {
                float4 v = srcp[qq];
                unsigned u0 = (unsigned)f2bf(v.x) | ((unsigned)f2bf(v.y) << 16);
                unsigned u1 = (unsigned)f2bf(v.z) | ((unsigned)f2bf(v.w) << 16);
                *(uint2*)(dstp + qq * 4) = make_uint2(u0, u1);
            }
        } else {
#pragma unroll
            for (int qq = 0; qq < 4; qq++) *(uint2*)(dstp + qq * 4) = make_uint2(0u, 0u);
        }
    }
    __syncthreads();

    const int tid = threadIdx.x;
    const int w = tid >> 6;
    const int l = tid & 63;
    const int mt = w & 1;               // m-tile (16 nodes)
    const int ctb = (w >> 1) * 4;       // 4 col-tiles of 16
    const int q = l >> 4;
    const int m16 = l & 15;

    floatx4 acc[3][4];
#pragma unroll
    for (int g = 0; g < 3; g++)
#pragma unroll
        for (int c = 0; c < 4; c++) acc[g][c] = (floatx4){0.f, 0.f, 0.f, 0.f};

    const unsigned short* arow = xs + (mt * 16 + m16) * XPAD + q * 8;
#pragma unroll
    for (int kc = 0; kc < 4; kc++) {
        short8 af = *(const short8*)(arow + kc * 32);
#pragma unroll
        for (int g = 0; g < 3; g++)
#pragma unroll
            for (int c = 0; c < 4; c++) {
                const unsigned short* bp = wf + ((((size_t)g * 8 + (ctb + c)) * 4 + kc) * 64 + l) * 8;
                short8 bv = *(const short8*)bp;
                acc[g][c] = __builtin_amdgcn_mfma_f32_16x16x32_bf16(af, bv, acc[g][c], 0, 0, 0);
            }
    }

#pragma unroll
    for (int c = 0; c < 4; c++) {
        const int col = (ctb + c) * 16 + m16;
        const float bi = bias[col], bg = bias[256 + col], bo = bias[384 + col];
#pragma unroll
        for (int r = 0; r < 4; r++) {
            const int node = nb + mt * 16 + q * 4 + r;
            if (node < N) {
                float iv = sigmoidf_(acc[0][c][r] + bi);
                float gv = tanhf(acc[1][c][r] + bg);
                float ov = sigmoidf_(acc[2][c][r] + bo);
                msg[(size_t)node * CCH + col] = f2bf(ov * tanhf(iv * gv));
            }
        }
    }
}

// ---------------- CSR build (both relations per launch) ----------------
__global__ __launch_bounds__(256) void hist_kernel(
    const int* __restrict__ dst0, const int* __restrict__ dst1,
    int* __restrict__ deg0, int* __restrict__ deg1, int E0, int E1)
{
    int e = blockIdx.x * 256 + threadIdx.x;
    if (e < E0) atomicAdd(&deg0[dst0[e]], 1);
    else if (e < E0 + E1) atomicAdd(&deg1[dst1[e - E0]], 1);
}

__global__ __launch_bounds__(256) void scan1_kernel(
    const int* __restrict__ deg0, const int* __restrict__ deg1,
    int* __restrict__ incl0, int* __restrict__ incl1,
    int* __restrict__ bsum, int N0, int N1, int nb0)
{
    __shared__ int s[256];
    const int rel = blockIdx.x >= nb0;
    const int blk = rel ? blockIdx.x - nb0 : blockIdx.x;
    const int* deg = rel ? deg1 : deg0;
    int* incl = rel ? incl1 : incl0;
    const int N = rel ? N1 : N0;
    const int tid = threadIdx.x;
    const int i = blk * 256 + tid;
    int v = (i < N) ? deg[i] : 0;
    s[tid] = v; __syncthreads();
#pragma unroll
    for (int off = 1; off < 256; off <<= 1) {
        int t = (tid >= off) ? s[tid - off] : 0;
        __syncthreads();
        s[tid] += t;
        __syncthreads();
    }
    if (i < N) incl[i] = s[tid];
    if (tid == 255) bsum[rel * 256 + blk] = s[255];
}

__global__ __launch_bounds__(256) void scan2_kernel(int* __restrict__ bsum, int nb0, int nb1)
{
    __shared__ int s[256];
    const int rel = blockIdx.x;
    const int nb = rel ? nb1 : nb0;
    int* bs = bsum + rel * 256;
    const int tid = threadIdx.x;
    int v = (tid < nb) ? bs[tid] : 0;
    s[tid] = v; __syncthreads();
#pragma unroll
    for (int off = 1; off < 256; off <<= 1) {
        int t = (tid >= off) ? s[tid - off] : 0;
        __syncthreads();
        s[tid] += t;
        __syncthreads();
    }
    if (tid < nb) bs[tid] = s[tid] - v;   // exclusive
}

__global__ __launch_bounds__(256) void scan3_kernel(
    const int* __restrict__ incl0, const int* __restrict__ incl1,
    const int* __restrict__ deg0, const int* __restrict__ deg1,
    const int* __restrict__ bsum,
    int* __restrict__ offs0, int* __restrict__ offs1,
    int* __restrict__ cur0, int* __restrict__ cur1,
    int N0, int N1, int nb0)
{
    const int rel = blockIdx.x >= nb0;
    const int blk = rel ? blockIdx.x - nb0 : blockIdx.x;
    const int i = blk * 256 + threadIdx.x;
    const int N = rel ? N1 : N0;
    if (i < N) {
        const int* incl = rel ? incl1 : incl0;
        const int* deg = rel ? deg1 : deg0;
        int o = incl[i] - deg[i] + bsum[rel * 256 + (i >> 8)];
        if (rel) { offs1[i] = o; cur1[i] = o; }
        else     { offs0[i] = o; cur0[i] = o; }
    }
}

__global__ __launch_bounds__(256) void fill_kernel(
    const int* __restrict__ src0, const int* __restrict__ dst0,
    const int* __restrict__ src1, const int* __restrict__ dst1,
    int* __restrict__ cur0, int* __restrict__ cur1,
    int* __restrict__ csr0, int* __restrict__ csr1, int E0, int E1)
{
    int e = blockIdx.x * 256 + threadIdx.x;
    if (e < E0) {
        int p = atomicAdd(&cur0[dst0[e]], 1);
        csr0[p] = src0[e];
    } else if (e < E0 + E1) {
        int ee = e - E0;
        int p = atomicAdd(&cur1[dst1[ee]], 1);
        csr1[p] = src1[ee];
    }
}

// ---------------- gather: one wave per dst node, bf16 msg ----------------
__global__ __launch_bounds__(256) void gather_kernel(
    const unsigned short* __restrict__ msg0, const unsigned short* __restrict__ msg1,
    const int* __restrict__ csr0, const int* __restrict__ csr1,
    const int* __restrict__ offs0, const int* __restrict__ offs1,
    const int* __restrict__ deg0, const int* __restrict__ deg1,
    unsigned short* __restrict__ aggr0, unsigned short* __restrict__ aggr1,
    int N0, int N1)
{
    const int wv = blockIdx.x * 4 + (threadIdx.x >> 6);
    const int l = threadIdx.x & 63;
    const unsigned short* msg; const int* csr; unsigned short* aggr;
    int n, start, cnt;
    if (wv < N0)            { n = wv;      msg = msg0; csr = csr0; start = offs0[n]; cnt = deg0[n]; aggr = aggr0; }
    else if (wv < N0 + N1)  { n = wv - N0; msg = msg1; csr = csr1; start = offs1[n]; cnt = deg1[n]; aggr = aggr1; }
    else return;

    float ax = 0.f, ay = 0.f;
    const int* ce = csr + start;
    const unsigned short* mb = msg + l * 2;
    int j = 0;
    for (; j + 4 <= cnt; j += 4) {
        int s0 = ce[j], s1 = ce[j + 1], s2 = ce[j + 2], s3 = ce[j + 3];
        unsigned u0 = *(const unsigned*)(mb + (size_t)s0 * CCH);
        unsigned u1 = *(const unsigned*)(mb + (size_t)s1 * CCH);
        unsigned u2 = *(const unsigned*)(mb + (size_t)s2 * CCH);
        unsigned u3 = *(const unsigned*)(mb + (size_t)s3 * CCH);
        ax += bf2f((unsigned short)u0) + bf2f((unsigned short)u1)
            + bf2f((unsigned short)u2) + bf2f((unsigned short)u3);
        ay += bf2f((unsigned short)(u0 >> 16)) + bf2f((unsigned short)(u1 >> 16))
            + bf2f((unsigned short)(u2 >> 16)) + bf2f((unsigned short)(u3 >> 16));
    }
    for (; j < cnt; j++) {
        unsigned u0 = *(const unsigned*)(mb + (size_t)ce[j] * CCH);
        ax += bf2f((unsigned short)u0);
        ay += bf2f((unsigned short)(u0 >> 16));
    }
    unsigned o = (unsigned)f2bf(ax) | ((unsigned)f2bf(ay) << 16);
    *(unsigned*)(aggr + (size_t)n * CCH + l * 2) = o;
}

// ---------------- final linear via MFMA ----------------
#define APAD 264   // 256 + 8 pad
__global__ __launch_bounds__(256) void linear_mfma_kernel(
    const float* __restrict__ xd0, const float* __restrict__ xd1,
    const unsigned short* __restrict__ ag0, const unsigned short* __restrict__ ag1,
    const unsigned short* __restrict__ wfrag,
    const float* __restrict__ bl0, const float* __restrict__ bl1,
    float* __restrict__ out0, float* __restrict__ out1,
    int N0, int N1, int nblk0)
{
    __shared__ unsigned short s[32 * APAD];
    const int rel = (blockIdx.x >= nblk0);
    const int nb = (rel ? blockIdx.x - nblk0 : blockIdx.x) * 32;
    const float* xd = rel ? xd1 : xd0;
    const unsigned short* ag = rel ? ag1 : ag0;
    const float* bl = rel ? bl1 : bl0;
    float* outp = rel ? out1 : out0;
    const int N = rel ? N1 : N0;
    const unsigned short* wf = wfrag + (size_t)rel * 4096 * 8;

    {   // stage [x_dst | aggr] as bf16
        int t = threadIdx.x;
        int r = t >> 3;
        int c0 = (t & 7) * 16;
        int n = nb + r;
        unsigned short* drow = s + r * APAD;
        if (n < N) {
            const float4* srcp = (const float4*)(xd + (size_t)n * CCH + c0);
#pragma unroll
            for (int qq = 0; qq < 4; qq++) {
                float4 v = srcp[qq];
                unsigned u0 = (unsigned)f2bf(v.x) | ((unsigned)f2bf(v.y) << 16);
                unsigned u1 = (unsigned)f2bf(v.z) | ((unsigned)f2bf(v.w) << 16);
                *(uint2*)(drow + c0 + qq * 4) = make_uint2(u0, u1);
            }
            const uint4* ap = (const uint4*)(ag + (size_t)n * CCH + c0);
            *(uint4*)(drow + CCH + c0) = ap[0];
            *(uint4*)(drow + CCH + c0 + 8) = ap[1];
        } else {
            uint4 z = make_uint4(0u, 0u, 0u, 0u);
            *(uint4*)(drow + c0) = z;
            *(uint4*)(drow + c0 + 8) = z;
            *(uint4*)(drow + CCH + c0) = z;
            *(uint4*)(drow + CCH + c0 + 8) = z;
        }
    }
    __syncthreads();

    const int tid = threadIdx.x;
    const int w = tid >> 6;
    const int l = tid & 63;
    const int mt = w & 1;
    const int ctb = (w >> 1) * 4;
    const int q = l >> 4;
    const int m16 = l & 15;

    floatx4 acc[4];
#pragma unroll
    for (int c = 0; c < 4; c++) acc[c] = (floatx4){0.f, 0.f, 0.f, 0.f};

    const unsigned short* arow = s + (mt * 16 + m16) * APAD + q * 8;
#pragma unroll
    for (int kc = 0; kc < 8; kc++) {
        short8 af = *(const short8*)(arow + kc * 32);
#pragma unroll
        for (int c = 0; c < 4; c++) {
            const unsigned short* bp = wf + ((((size_t)(ctb + c)) * 8 + kc) * 64 + l) * 8;
            short8 bv = *(const short8*)bp;
            acc[c] = __builtin_amdgcn_mfma_f32_16x16x32_bf16(af, bv, acc[c], 0, 0, 0);
        }
    }

#pragma unroll
    for (int c = 0; c < 4; c++) {
        const int col = (ctb + c) * 16 + m16;
        const float bv = bl[col];
#pragma unroll
        for (int r = 0; r < 4; r++) {
            const int node = nb + mt * 16 + q * 4 + r;
            if (node < N) outp[(size_t)node * CCH + col] = fmaxf(acc[c][r] + bv, 0.0f);
        }
    }
}

extern "C" void kernel_launch(void* const* d_in, const int* in_sizes, int n_in,
                              void* d_out, int out_size, void* d_ws, size_t ws_size,
                              hipStream_t stream) {
    const float* x_a      = (const float*)d_in[0];
    const float* x_b      = (const float*)d_in[1];
    const int*   e_ab     = (const int*)d_in[2];
    const int*   e_ba     = (const int*)d_in[3];
    const float* W_ih_ab  = (const float*)d_in[4];
    const float* b_ab     = (const float*)d_in[5];
    const float* W_lin_ab = (const float*)d_in[6];
    const float* b_lin_ab = (const float*)d_in[7];
    const float* W_ih_ba  = (const float*)d_in[8];
    const float* b_ba     = (const float*)d_in[9];
    const float* W_lin_ba = (const float*)d_in[10];
    const float* b_lin_ba = (const float*)d_in[11];

    const int NA = in_sizes[0] / CCH;
    const int NB = in_sizes[1] / CCH;
    const int E0 = in_sizes[2] / 2;   // a->b
    const int E1 = in_sizes[3] / 2;   // b->a

    float* out = (float*)d_out;
    char* ws = (char*)d_ws;
    size_t off = 0;
    auto alloc = [&](size_t bytes) { char* p = ws + off; off += (bytes + 255) & ~(size_t)255; return p; };

    unsigned short* wfrag_ih  = (unsigned short*)alloc(12288 * 8 * 2);
    unsigned short* wfrag_lin = (unsigned short*)alloc(8192 * 8 * 2);
    unsigned short* msg_a     = (unsigned short*)alloc((size_t)NA * CCH * 2);
    unsigned short* msg_b     = (unsigned short*)alloc((size_t)NB * CCH * 2);
    unsigned short* aggr_b    = (unsigned short*)alloc((size_t)NB * CCH * 2);
    unsigned short* aggr_a    = (unsigned short*)alloc((size_t)NA * CCH * 2);
    int* deg_b  = (int*)alloc((size_t)NB * 4);   // deg_b/deg_a adjacent for one memset
    int* deg_a  = (int*)alloc((size_t)NA * 4);
    int* incl_b = (int*)alloc((size_t)NB * 4);
    int* incl_a = (int*)alloc((size_t)NA * 4);
    int* bsum   = (int*)alloc(2 * 256 * 4);
    int* offs_b = (int*)alloc((size_t)NB * 4);
    int* offs_a = (int*)alloc((size_t)NA * 4);
    int* cur_b  = (int*)alloc((size_t)NB * 4);
    int* cur_a  = (int*)alloc((size_t)NA * 4);
    int* csr_ab = (int*)alloc((size_t)E0 * 4);
    int* csr_ba = (int*)alloc((size_t)E1 * 4);

    const int nbB = (NB + 255) / 256;
    const int nbA = (NA + 255) / 256;
    const int nblkA = (NA + 31) / 32;
    const int nblkB = (NB + 31) / 32;

    // zero degree histograms (deg_b padded to 256 then deg_a)
    const size_t degB_pad = ((size_t)NB * 4 + 255) & ~(size_t)255;
    hipMemsetAsync(deg_b, 0, degB_pad + (size_t)NA * 4, stream);

    prep_wih_kernel<<<48, 256, 0, stream>>>(W_ih_ab, W_ih_ba, wfrag_ih);
    prep_wlin_kernel<<<32, 256, 0, stream>>>(W_lin_ab, W_lin_ba, wfrag_lin);

    // rel0: a->b (src A, msg_a); rel1: b->a (src B, msg_b)
    lstm_mfma_kernel<<<nblkA + nblkB, 256, 0, stream>>>(
        x_a, x_b, wfrag_ih, b_ab, b_ba, msg_a, msg_b, NA, NB, nblkA);

    hist_kernel<<<(E0 + E1 + 255) / 256, 256, 0, stream>>>(
        e_ab + E0, e_ba + E1, deg_b, deg_a, E0, E1);
    scan1_kernel<<<nbB + nbA, 256, 0, stream>>>(deg_b, deg_a, incl_b, incl_a, bsum, NB, NA, nbB);
    scan2_kernel<<<2, 256, 0, stream>>>(bsum, nbB, nbA);
    scan3_kernel<<<nbB + nbA, 256, 0, stream>>>(
        incl_b, incl_a, deg_b, deg_a, bsum, offs_b, offs_a, cur_b, cur_a, NB, NA, nbB);
    fill_kernel<<<(E0 + E1 + 255) / 256, 256, 0, stream>>>(
        e_ab, e_ab + E0, e_ba, e_ba + E1, cur_b, cur_a, csr_ab, csr_ba, E0, E1);

    gather_kernel<<<(NB + NA + 3) / 4, 256, 0, stream>>>(
        msg_a, msg_b, csr_ab, csr_ba, offs_b, offs_a, deg_b, deg_a, aggr_b, aggr_a, NB, NA);

    // rel0 output -> out_b (index 1), rel1 -> out_a (index 0)
    linear_mfma_kernel<<<nblkB + nblkA, 256, 0, stream>>>(
        x_b, x_a, aggr_b, aggr_a, wfrag_lin, b_lin_ab, b_lin_ba,
        out + (size_t)NA * CCH, out, NB, NA, nblkB);
}